// Round 3
// baseline (16443.318 us; speedup 1.0000x reference)
//
#include <hip/hip_runtime.h>

#define N_NODES 50000
#define N_EDGES 1600000
#define N_GRAPHS 1024
#define HID 64
#define EDGE_F 16
#define LN_EPS 1e-5f

__device__ __forceinline__ float silu_f(float x) {
    return x / (1.0f + __expf(-x));
}

// acc[k] += scale * x[j] * w[j*HID + k], j = 0..4*NJ4-1
// w accesses are wave-uniform -> compiler emits s_load + SGPR-operand v_fma.
template<int NJ4>
__device__ __forceinline__ void gemv_acc(const float4* __restrict__ x,
                                         const float* __restrict__ w,
                                         float scale, float* __restrict__ acc) {
    for (int j4 = 0; j4 < NJ4; ++j4) {
        float4 v = x[j4];
        v.x *= scale; v.y *= scale; v.z *= scale; v.w *= scale;
        const float* wr = w + j4 * 4 * HID;
        #pragma unroll
        for (int k = 0; k < HID; ++k) acc[k] = fmaf(v.x, wr[k],         acc[k]);
        #pragma unroll
        for (int k = 0; k < HID; ++k) acc[k] = fmaf(v.y, wr[HID + k],   acc[k]);
        #pragma unroll
        for (int k = 0; k < HID; ++k) acc[k] = fmaf(v.z, wr[2*HID + k], acc[k]);
        #pragma unroll
        for (int k = 0; k < HID; ++k) acc[k] = fmaf(v.w, wr[3*HID + k], acc[k]);
    }
}

// One thread per edge: msg = silu([h[s], h[d], dij, ea] @ Wm + bm); atomicAdd into agg[d].
__global__ __launch_bounds__(256) void edge_kernel(
    const float* __restrict__ h, const float* __restrict__ pos,
    const float* __restrict__ edge_attr, const int* __restrict__ src,
    const int* __restrict__ dst, const float* __restrict__ Wm,
    const float* __restrict__ bm, float* __restrict__ agg)
{
    int e = blockIdx.x * 256 + threadIdx.x;
    if (e >= N_EDGES) return;
    int s = src[e], d = dst[e];

    float px = pos[3*s+0] - pos[3*d+0];
    float py = pos[3*s+1] - pos[3*d+1];
    float pz = pos[3*s+2] - pos[3*d+2];
    float dij = sqrtf(fmaxf(px*px + py*py + pz*pz, 1e-8f));

    float acc[HID];
    #pragma unroll
    for (int k = 0; k < HID; ++k) acc[k] = bm[k];

    gemv_acc<16>((const float4*)(h + (size_t)s * HID), Wm,            1.0f, acc);
    gemv_acc<16>((const float4*)(h + (size_t)d * HID), Wm + 64*HID,   1.0f, acc);
    {
        const float* wr = Wm + 128*HID;
        #pragma unroll
        for (int k = 0; k < HID; ++k) acc[k] = fmaf(dij, wr[k], acc[k]);
    }
    gemv_acc<4>((const float4*)(edge_attr + (size_t)e * EDGE_F), Wm + 129*HID, 1.0f, acc);

    float* a = agg + (size_t)d * HID;
    #pragma unroll
    for (int k = 0; k < HID; ++k) atomicAdd(a + k, silu_f(acc[k]));
}

// One thread per node: u = silu((agg/10) @ Wu + bu); h_out = LN(u)*g + b. In-place on agg.
__global__ __launch_bounds__(256) void node_kernel(
    float* __restrict__ agg, const float* __restrict__ Wu,
    const float* __restrict__ bu, const float* __restrict__ g,
    const float* __restrict__ b)
{
    int n = blockIdx.x * 256 + threadIdx.x;
    if (n >= N_NODES) return;
    float acc[HID];
    #pragma unroll
    for (int k = 0; k < HID; ++k) acc[k] = bu[k];
    gemv_acc<16>((const float4*)(agg + (size_t)n * HID), Wu, 0.1f, acc);

    float mu = 0.f;
    #pragma unroll
    for (int k = 0; k < HID; ++k) { acc[k] = silu_f(acc[k]); mu += acc[k]; }
    mu *= (1.0f / HID);
    float var = 0.f;
    #pragma unroll
    for (int k = 0; k < HID; ++k) { float t = acc[k] - mu; var += t * t; }
    var *= (1.0f / HID);
    float rs = rsqrtf(var + LN_EPS);

    float* o = agg + (size_t)n * HID;
    #pragma unroll
    for (int k = 0; k < HID; ++k) o[k] = fmaf(g[k], (acc[k] - mu) * rs, b[k]);
}

// 64 lanes per node, lane k handles feature k; graph_ids sorted -> decent locality.
__global__ __launch_bounds__(256) void gsum_kernel(
    const float* __restrict__ h, const int* __restrict__ gid, float* __restrict__ gf)
{
    int t = blockIdx.x * 256 + threadIdx.x;
    int n = t >> 6, k = t & 63;
    if (n >= N_NODES) return;
    atomicAdd(gf + gid[n] * HID + k, h[(size_t)n * HID + k] * 0.1f);
}

// One thread per graph: out = silu(gf @ Wh1 + bh1) @ Wh2 + bh2
__global__ __launch_bounds__(256) void head_kernel(
    const float* __restrict__ gf, const float* __restrict__ Wh1,
    const float* __restrict__ bh1, const float* __restrict__ Wh2,
    const float* __restrict__ bh2, float* __restrict__ out)
{
    int gi = blockIdx.x * 256 + threadIdx.x;
    if (gi >= N_GRAPHS) return;
    float x[HID];
    const float4* xr = (const float4*)(gf + (size_t)gi * HID);
    #pragma unroll
    for (int j4 = 0; j4 < 16; ++j4) {
        float4 v = xr[j4];
        x[4*j4] = v.x; x[4*j4+1] = v.y; x[4*j4+2] = v.z; x[4*j4+3] = v.w;
    }
    float o = bh2[0];
    #pragma unroll 4
    for (int j = 0; j < 32; ++j) {
        float hs_ = bh1[j];
        #pragma unroll
        for (int k = 0; k < HID; ++k) hs_ = fmaf(x[k], Wh1[k*32 + j], hs_);
        o = fmaf(silu_f(hs_), Wh2[j], o);
    }
    out[gi] = o;
}

extern "C" void kernel_launch(void* const* d_in, const int* in_sizes, int n_in,
                              void* d_out, int out_size, void* d_ws, size_t ws_size,
                              hipStream_t stream)
{
    const float* node_attr = (const float*)d_in[0];
    const float* pos       = (const float*)d_in[1];
    const float* edge_attr = (const float*)d_in[2];
    const int*   src       = (const int*)d_in[3];
    const int*   dst       = (const int*)d_in[4];
    const int*   gid       = (const int*)d_in[5];
    const float* Wm        = (const float*)d_in[6];
    const float* bm        = (const float*)d_in[7];
    const float* Wu        = (const float*)d_in[8];
    const float* bu        = (const float*)d_in[9];
    const float* ln_g      = (const float*)d_in[10];
    const float* ln_b      = (const float*)d_in[11];
    const float* Wh1       = (const float*)d_in[12];
    const float* bh1       = (const float*)d_in[13];
    const float* Wh2       = (const float*)d_in[14];
    const float* bh2       = (const float*)d_in[15];
    float* out = (float*)d_out;

    float* B1 = (float*)d_ws;                       // N_NODES*HID f32
    float* B2 = B1 + (size_t)N_NODES * HID;         // N_NODES*HID f32
    float* gf = B2 + (size_t)N_NODES * HID;         // N_GRAPHS*HID f32

    const int EB = N_EDGES / 256;            // 6250 exact
    const int NB = (N_NODES + 255) / 256;    // 196

    const float* hin = node_attr;
    float* bufs[3] = { B1, B2, B1 };
    for (int i = 0; i < 3; ++i) {
        float* agg = bufs[i];
        hipMemsetAsync(agg, 0, (size_t)N_NODES * HID * sizeof(float), stream);
        edge_kernel<<<EB, 256, 0, stream>>>(hin, pos, edge_attr, src, dst,
                                            Wm + (size_t)i * 145 * HID, bm + i * HID, agg);
        node_kernel<<<NB, 256, 0, stream>>>(agg, Wu + (size_t)i * HID * HID, bu + i * HID,
                                            ln_g + i * HID, ln_b + i * HID);
        hin = agg;
    }
    hipMemsetAsync(gf, 0, (size_t)N_GRAPHS * HID * sizeof(float), stream);
    gsum_kernel<<<(N_NODES * 64) / 256, 256, 0, stream>>>(hin, gid, gf);
    head_kernel<<<(N_GRAPHS + 255) / 256, 256, 0, stream>>>(gf, Wh1, bh1, Wh2, bh2, out);
}